// Round 7
// baseline (449.996 us; speedup 1.0000x reference)
//
#include <hip/hip_runtime.h>
#include <math.h>

#define BB 8
#define LL 1024
#define DD 768
#define NNs 16
#define RR 48

typedef __attribute__((ext_vector_type(8))) short bf16x8;
typedef __attribute__((ext_vector_type(4))) float f32x4;

__device__ __forceinline__ float silu_f(float v) { return v / (1.0f + __expf(-v)); }

__device__ __forceinline__ short f2bf(float f) {
    union { float f; unsigned u; } v; v.f = f;
    unsigned r = (v.u + 0x7fffu + ((v.u >> 16) & 1u)) >> 16;
    return (short)r;
}

__device__ __forceinline__ void async16(const void* g, void* l) {
    __builtin_amdgcn_global_load_lds((const __attribute__((address_space(1))) void*)g,
                                     (__attribute__((address_space(3))) void*)l,
                                     16, 0, 0);
}

// ---------------------------------------------------------------------------
// K0: fp32 -> bf16 weight conversion
// ---------------------------------------------------------------------------
__global__ __launch_bounds__(256) void k_cvt(const float* __restrict__ src,
                                             short* __restrict__ dst, int n4) {
    int i = blockIdx.x * 256 + threadIdx.x;
    if (i < n4) {
        float4 v = ((const float4*)src)[i];
        short4 o = { f2bf(v.x), f2bf(v.y), f2bf(v.z), f2bf(v.w) };
        ((short4*)dst)[i] = o;
    }
}

// ---------------------------------------------------------------------------
// K1: pos embedding (analytic; batch_params/has_velocity provably cancel) +
// residual + RMSNorm. res fp32, hidden bf16.
// ---------------------------------------------------------------------------
__global__ __launch_bounds__(256) void k_pos_rms(const float* __restrict__ x,
                                                 const float* __restrict__ norm_w,
                                                 float* __restrict__ res,
                                                 short* __restrict__ hidb) {
    int row = blockIdx.x;
    int l = row & (LL - 1);
    int d3 = l & 3;
    int w = (l >> 2) & 15;
    int h = l >> 6;
    float coord[3] = { h * (1.0f / 15.0f), w * (1.0f / 15.0f), d3 * (1.0f / 3.0f) };
    const float LOG1E4 = 9.210340371976184f;
    int t = threadIdx.x;
    float r[3];
    float s = 0.0f;
#pragma unroll
    for (int i = 0; i < 3; i++) {
        int j = t + i * 256;
        int c = j >> 8;
        int fp = j & 255;
        int f = fp & 127;
        float omega = __expf(-(f * (1.0f / 128.0f)) * LOG1E4);
        float arg = coord[c] * omega;
        float pv = (fp < 128) ? __sinf(arg) : __cosf(arg);
        float rv = x[(size_t)row * DD + j] + pv;
        r[i] = rv;
        s += rv * rv;
    }
#pragma unroll
    for (int off = 32; off; off >>= 1) s += __shfl_xor(s, off, 64);
    __shared__ float ls[4];
    if ((t & 63) == 0) ls[t >> 6] = s;
    __syncthreads();
    s = ls[0] + ls[1] + ls[2] + ls[3];
    float rs = rsqrtf(s * (1.0f / DD) + 1e-5f);
#pragma unroll
    for (int i = 0; i < 3; i++) {
        int j = t + i * 256;
        res[(size_t)row * DD + j] = r[i];
        hidb[(size_t)row * DD + j] = f2bf(r[i] * rs * norm_w[j]);
    }
}

// ---------------------------------------------------------------------------
// MFMA bf16 GEMM (NT), 128x128 tile, BK=32, 4 waves. AF32: A is fp32 and is
// converted to bf16 during LDS staging (out_proj path); else async16 staging.
// EPI 1 (in_proj): +bias; n<768 -> C0 (b,t,d); n>=768 -> C1 (b,t,d).
// EPI 3 (out_proj): +bias +resid -> C0.
// ---------------------------------------------------------------------------
template <int EPI, bool AF32>
__global__ __launch_bounds__(256) void gemm_mfma(const void* __restrict__ Ap,
                                                 const short* __restrict__ Bw,
                                                 int Kd,
                                                 const float* __restrict__ bias,
                                                 const float* __restrict__ resid,
                                                 float* __restrict__ C0,
                                                 float* __restrict__ C1) {
    __shared__ short As[4096];   // 128 rows x 32 k, fragment-ordered
    __shared__ short Bs[4096];
    int m0 = blockIdx.y * 128;
    int n0 = blockIdx.x * 128;
    int tid = threadIdx.x;
    int lane = tid & 63, wave = tid >> 6;
    int q = lane >> 4, r = lane & 15;
    int wm = wave >> 1, wn = wave & 1;

    const size_t Kb = (size_t)Kd * 2;
    const char* gB0 = (const char*)Bw + (size_t)(n0 + wave * 16 + r) * Kb + q * 16;
    const char* gB1 = gB0 + 64 * Kb;
    char* lB0 = (char*)Bs + wave * 1024;
    char* lB1 = lB0 + 4096;
    const char* gA0 = nullptr; const char* gA1 = nullptr;
    char* lA0 = nullptr; char* lA1 = nullptr;
    if (!AF32) {
        gA0 = (const char*)Ap + (size_t)(m0 + wave * 16 + r) * Kb + q * 16;
        gA1 = gA0 + 64 * Kb;
        lA0 = (char*)As + wave * 1024;
        lA1 = lA0 + 4096;
    }

    f32x4 acc[4][4] = {};

    for (int k0 = 0; k0 < Kd; k0 += 32) {
        if (AF32) {
            const float* Af = (const float*)Ap;
#pragma unroll
            for (int p = 0; p < 2; p++) {
                int m = m0 + (p * 4 + wave) * 16 + r;
                const float* src = Af + (size_t)m * Kd + k0 + q * 8;
                float4 v0 = *(const float4*)src;
                float4 v1 = *(const float4*)(src + 4);
                bf16x8 pk;
                pk[0] = f2bf(v0.x); pk[1] = f2bf(v0.y);
                pk[2] = f2bf(v0.z); pk[3] = f2bf(v0.w);
                pk[4] = f2bf(v1.x); pk[5] = f2bf(v1.y);
                pk[6] = f2bf(v1.z); pk[7] = f2bf(v1.w);
                *(bf16x8*)&As[p * 2048 + wave * 512 + lane * 8] = pk;
            }
        } else {
            async16(gA0, lA0); async16(gA1, lA1);
            gA0 += 64; gA1 += 64;
        }
        async16(gB0, lB0); async16(gB1, lB1);
        gB0 += 64; gB1 += 64;
        __syncthreads();
        bf16x8 af[4], bf[4];
#pragma unroll
        for (int a = 0; a < 4; a++)
            af[a] = *(const bf16x8*)&As[((wm * 4 + a) * 64 + q * 16 + r) * 8];
#pragma unroll
        for (int b = 0; b < 4; b++)
            bf[b] = *(const bf16x8*)&Bs[((wn * 4 + b) * 64 + q * 16 + r) * 8];
#pragma unroll
        for (int a = 0; a < 4; a++)
#pragma unroll
            for (int b = 0; b < 4; b++)
                acc[a][b] = __builtin_amdgcn_mfma_f32_16x16x32_bf16(
                    af[a], bf[b], acc[a][b], 0, 0, 0);
        __syncthreads();
    }

    // C/D layout: col(n) = lane&15, row(m) = (lane>>4)*4 + reg  [m89/m91]
#pragma unroll
    for (int a = 0; a < 4; a++) {
        int mrow = m0 + (wm * 4 + a) * 16 + q * 4;
#pragma unroll
        for (int b = 0; b < 4; b++) {
            int ncol = n0 + (wn * 4 + b) * 16 + r;
            float bb = bias[ncol];
            if (EPI == 1) {
                float* dst = (ncol < DD) ? (C0 + (size_t)mrow * DD + ncol)
                                         : (C1 + (size_t)mrow * DD + (ncol - DD));
#pragma unroll
                for (int e = 0; e < 4; e++)
                    dst[(size_t)e * DD] = acc[a][b][e] + bb;
            } else {
#pragma unroll
                for (int e = 0; e < 4; e++) {
                    size_t idx = (size_t)(mrow + e) * DD + ncol;
                    C0[idx] = acc[a][b][e] + bb + resid[idx];
                }
            }
        }
    }
}

// ---------------------------------------------------------------------------
// fp32 NT GEMM. MODE 0 (x_proj): plain store with n<N guard.
// MODE 2 (dt_proj): softplus, float4 store to (b,t,d).
// ---------------------------------------------------------------------------
template <int MODE>
__global__ __launch_bounds__(256) void gemm_nt(const float* __restrict__ A, int lda,
                                               const float* __restrict__ Bw, int ldb,
                                               int N, int Kd,
                                               const float* __restrict__ bias,
                                               float* __restrict__ C0, int ldc) {
    __shared__ __align__(16) float As[16][68];
    __shared__ __align__(16) float Bs[16][68];
    int m0 = blockIdx.y * 64;
    int n0 = blockIdx.x * 64;
    int t = threadIdx.x;
    int tx = t & 15, ty = t >> 4;
    int ar = t >> 2;
    int ak = (t & 3) * 4;
    float acc[4][4] = {};
    for (int k0 = 0; k0 < Kd; k0 += 16) {
        float4 av = *(const float4*)(A + (size_t)(m0 + ar) * lda + k0 + ak);
        int brow = n0 + ar;
        if (brow >= N) brow = N - 1;
        float4 bv = *(const float4*)(Bw + (size_t)brow * ldb + k0 + ak);
        As[ak + 0][ar] = av.x; As[ak + 1][ar] = av.y;
        As[ak + 2][ar] = av.z; As[ak + 3][ar] = av.w;
        Bs[ak + 0][ar] = bv.x; Bs[ak + 1][ar] = bv.y;
        Bs[ak + 2][ar] = bv.z; Bs[ak + 3][ar] = bv.w;
        __syncthreads();
#pragma unroll
        for (int kk = 0; kk < 16; kk++) {
            float4 a4 = *(const float4*)&As[kk][ty * 4];
            float4 b4 = *(const float4*)&Bs[kk][tx * 4];
            float aa[4] = { a4.x, a4.y, a4.z, a4.w };
            float bb[4] = { b4.x, b4.y, b4.z, b4.w };
#pragma unroll
            for (int i = 0; i < 4; i++)
#pragma unroll
                for (int j = 0; j < 4; j++) acc[i][j] += aa[i] * bb[j];
        }
        __syncthreads();
    }
    if (MODE == 0) {
#pragma unroll
        for (int i = 0; i < 4; i++) {
            int m = m0 + ty * 4 + i;
#pragma unroll
            for (int j = 0; j < 4; j++) {
                int n = n0 + tx * 4 + j;
                if (n < N) C0[(size_t)m * ldc + n] = acc[i][j];
            }
        }
    } else {
        float4 bi = *(const float4*)(bias + n0 + tx * 4);
        float bl[4] = { bi.x, bi.y, bi.z, bi.w };
#pragma unroll
        for (int i = 0; i < 4; i++) {
            int m = m0 + ty * 4 + i;
            float v[4];
#pragma unroll
            for (int j = 0; j < 4; j++) {
                float u = acc[i][j] + bl[j];
                v[j] = (u > 20.0f) ? u : log1pf(__expf(u));
            }
            float4 o = { v[0], v[1], v[2], v[3] };
            *(float4*)(C0 + (size_t)m * DD + n0 + tx * 4) = o;
        }
    }
}

// ---------------------------------------------------------------------------
// K3: depthwise causal conv (K=4) + bias + silu, (b,t,d) -> (b,t,d)
// ---------------------------------------------------------------------------
__global__ __launch_bounds__(256) void k_conv(const float* __restrict__ xin,
                                              const float* __restrict__ cw,
                                              const float* __restrict__ cb,
                                              float* __restrict__ xc) {
    size_t gid = (size_t)blockIdx.x * 256 + threadIdx.x;
    int d = (int)(gid % DD);
    int bt = (int)(gid / DD);
    int tt = bt & (LL - 1);
    float4 w = ((const float4*)cw)[d];
    const float* p = xin + (size_t)bt * DD + d;
    float acc = cb[d];
    if (tt >= 3) acc += p[-3 * DD] * w.x;
    if (tt >= 2) acc += p[-2 * DD] * w.y;
    if (tt >= 1) acc += p[-1 * DD] * w.z;
    acc += p[0] * w.w;
    xc[gid] = silu_f(acc);
}

// ---------------------------------------------------------------------------
// K5: register-state chunked selective scan, v4 — async-staged tiles.
// Block = 16 d x 16 chunks (64 t each); one thread per (b,d,chunk) holds all
// 16 n-states in VGPRs.  Per 8-t group the block stages the dt/xc(/z) tiles
// (128 rows x 16 d, full 64 B rows) + B/C rows via global_load_lds(16B) into
// LDS, then computes 8 steps from LDS — batching ~100 64 B requests per wave
// per group instead of 2-3 serial loads per timestep (latency fix).
// One 40 KB LDS buffer aliased: staging (phases 1/3) | P,S + H (combine).
// exp via exp2f with log2e folded into Ac (native v_exp_f32, args <= 0).
// ---------------------------------------------------------------------------
__global__ __launch_bounds__(256) void k_scan(const float* __restrict__ dtf,
                                              const float* __restrict__ xc,
                                              const float* __restrict__ xdbl,
                                              const float* __restrict__ A_log,
                                              const float* __restrict__ Dp,
                                              float* __restrict__ zy) {
    __shared__ float buf[10240];           // 40 KB
    int b = blockIdx.y;
    int d0 = blockIdx.x * 16;
    int tid = threadIdx.x;
    int lane = tid & 63, wave = tid >> 6;
    int dl = tid & 15;
    int c = tid >> 4;                      // chunk 0..15
    int d = d0 + dl;

    float Ac2[16];                          // -exp(A_log) * log2(e)
    {
        const float4* al = (const float4*)(A_log + d * NNs);
#pragma unroll
        for (int i = 0; i < 4; i++) {
            float4 v = al[i];
            Ac2[i * 4 + 0] = -__expf(v.x) * 1.44269504f;
            Ac2[i * 4 + 1] = -__expf(v.y) * 1.44269504f;
            Ac2[i * 4 + 2] = -__expf(v.z) * 1.44269504f;
            Ac2[i * 4 + 3] = -__expf(v.w) * 1.44269504f;
        }
    }
    const float* xb = xdbl + (size_t)b * LL * 80;
    size_t rowbase = (size_t)b * LL;

    int r0 = wave * 16 + (lane >> 2);      // staging row, issue p adds 64
    int lc = (lane & 3) * 16;              // byte offset within 64 B row

    // ---- Phase 1: local scan from zero state, staged per 8-t group
    float P[16], S[16];
#pragma unroll
    for (int n = 0; n < 16; n++) { P[n] = 1.0f; S[n] = 0.0f; }
    for (int g = 0; g < 64; g += 8) {
#pragma unroll
        for (int p = 0; p < 2; p++) {
            int rr = r0 + p * 64;
            int t = (rr >> 3) * 64 + g + (rr & 7);
            char* dbase = (char*)buf + p * 4096 + wave * 1024;
            async16((const char*)(dtf + (rowbase + t) * DD + d0) + lc, dbase);
            async16((const char*)(xc + (rowbase + t) * DD + d0) + lc, dbase + 8192);
            async16((const char*)(xb + (size_t)t * 80 + RR) + lc, dbase + 16384);
        }
        __syncthreads();
        for (int i = 0; i < 8; i++) {
            int ro = (c * 8 + i) * 16;
            float dtv = buf[ro + dl];
            float xcv = buf[2048 + ro + dl];
            float dx = dtv * xcv;
#pragma unroll
            for (int qq = 0; qq < 4; qq++) {
                float4 B4 = *(const float4*)&buf[4096 + ro + qq * 4];
                float bl[4] = { B4.x, B4.y, B4.z, B4.w };
#pragma unroll
                for (int j = 0; j < 4; j++) {
                    int n = qq * 4 + j;
                    float e = exp2f(dtv * Ac2[n]);
                    P[n] *= e;
                    S[n] = e * S[n] + dx * bl[j];
                }
            }
        }
        __syncthreads();
    }
    // write P,S into combine area: P -> buf[0:4096], S -> buf[4096:8192]
    {
        int base = (c * 16 + dl) * 16;
#pragma unroll
        for (int qq = 0; qq < 4; qq++) {
            float4 pv = { P[qq * 4], P[qq * 4 + 1], P[qq * 4 + 2], P[qq * 4 + 3] };
            float4 sv = { S[qq * 4], S[qq * 4 + 1], S[qq * 4 + 2], S[qq * 4 + 3] };
            *(float4*)&buf[base + qq * 4] = pv;
            *(float4*)&buf[4096 + base + qq * 4] = sv;
        }
    }
    __syncthreads();
    // ---- Phase 2: serial combine per (d,n); H overwrites P area
    {
        int d2 = tid >> 4, n2 = tid & 15;
        float hh = 0.0f;
#pragma unroll
        for (int cc = 0; cc < 16; cc++) {
            int idx = (cc * 16 + d2) * 16 + n2;
            float Pv = buf[idx], Sv = buf[4096 + idx];
            buf[idx] = hh;
            hh = Pv * hh + Sv;
        }
    }
    __syncthreads();
    float h[16];
    {
        const float* hr = &buf[(c * 16 + dl) * 16];
#pragma unroll
        for (int qq = 0; qq < 4; qq++) {
            float4 v = *(const float4*)(hr + qq * 4);
            h[qq * 4] = v.x; h[qq * 4 + 1] = v.y;
            h[qq * 4 + 2] = v.z; h[qq * 4 + 3] = v.w;
        }
    }
    __syncthreads();                       // all H read before staging reuse
    float Dv = Dp[d];
    // ---- Phase 3: rescan from h_in, gate, write in place
    for (int g = 0; g < 64; g += 8) {
#pragma unroll
        for (int p = 0; p < 2; p++) {
            int rr = r0 + p * 64;
            int t = (rr >> 3) * 64 + g + (rr & 7);
            char* dbase = (char*)buf + p * 4096 + wave * 1024;
            async16((const char*)(dtf + (rowbase + t) * DD + d0) + lc, dbase);
            async16((const char*)(xc + (rowbase + t) * DD + d0) + lc, dbase + 8192);
            async16((const char*)(zy + (rowbase + t) * DD + d0) + lc, dbase + 16384);
            async16((const char*)(xb + (size_t)t * 80 + RR) + lc, dbase + 24576);
            async16((const char*)(xb + (size_t)t * 80 + RR + 16) + lc, dbase + 32768);
        }
        __syncthreads();
        for (int i = 0; i < 8; i++) {
            int ro = (c * 8 + i) * 16;
            float dtv = buf[ro + dl];
            float xcv = buf[2048 + ro + dl];
            float zv  = buf[4096 + ro + dl];
            float dx = dtv * xcv;
            float y = Dv * xcv;
#pragma unroll
            for (int qq = 0; qq < 4; qq++) {
                float4 B4 = *(const float4*)&buf[6144 + ro + qq * 4];
                float4 C4 = *(const float4*)&buf[8192 + ro + qq * 4];
                float bl[4] = { B4.x, B4.y, B4.z, B4.w };
                float cl[4] = { C4.x, C4.y, C4.z, C4.w };
#pragma unroll
                for (int j = 0; j < 4; j++) {
                    int n = qq * 4 + j;
                    float e = exp2f(dtv * Ac2[n]);
                    h[n] = e * h[n] + dx * bl[j];
                    y += h[n] * cl[j];
                }
            }
            int t = c * 64 + g + i;
            zy[(rowbase + t) * DD + d] = y * silu_f(zv);
        }
        __syncthreads();
    }
}

// ---------------------------------------------------------------------------
extern "C" void kernel_launch(void* const* d_in, const int* in_sizes, int n_in,
                              void* d_out, int out_size, void* d_ws, size_t ws_size,
                              hipStream_t stream) {
    const float* x      = (const float*)d_in[0];
    // d_in[1] batch_params, d_in[2] has_velocity: provably no effect
    const float* norm_w = (const float*)d_in[3];
    const float* in_w   = (const float*)d_in[4];
    const float* in_b   = (const float*)d_in[5];
    const float* conv_w = (const float*)d_in[6];
    const float* conv_b = (const float*)d_in[7];
    const float* xp_w   = (const float*)d_in[8];
    const float* dt_w   = (const float*)d_in[9];
    const float* dt_b   = (const float*)d_in[10];
    const float* A_log  = (const float*)d_in[11];
    const float* Dp     = (const float*)d_in[12];
    const float* out_w  = (const float*)d_in[13];
    const float* out_b  = (const float*)d_in[14];
    float* out = (float*)d_out;

    const size_t S = (size_t)BB * LL * DD;     // 6291456
    float* res   = (float*)d_ws;               // residual (fp32)
    float* slotA = res + S;                    // hidb (bf16) then xc (fp32)
    float* slotB = slotA + S;                  // xin then dtf (fp32)
    float* zf    = slotB + S;                  // z (b,t,d); gated y in place
    float* xdbl  = zf + S;                     // (B*L, 80)
    short* inw_b  = (short*)(xdbl + (size_t)BB * LL * 80);   // 1536x768 bf16
    short* outw_b = inw_b + 1536 * DD;                       // 768x768 bf16

    short* hidb = (short*)slotA;
    float* xc   = slotA;
    float* xin  = slotB;
    float* dtf  = slotB;

    const int M = BB * LL;                     // 8192

    // 0. weight conversions
    k_cvt<<<(1536 * DD / 4 + 255) / 256, 256, 0, stream>>>(in_w, inw_b, 1536 * DD / 4);
    k_cvt<<<(DD * DD / 4 + 255) / 256, 256, 0, stream>>>(out_w, outw_b, DD * DD / 4);

    // 1. pos + residual + rmsnorm (hidden bf16)
    k_pos_rms<<<M, 256, 0, stream>>>(x, norm_w, res, hidb);

    // 2. in_proj (MFMA): -> xin (b,t,d) | zf (b,t,d)
    gemm_mfma<1, false><<<dim3(1536 / 128, M / 128), 256, 0, stream>>>(
        hidb, inw_b, DD, in_b, nullptr, xin, zf);

    // 3. depthwise conv + silu: xin -> xc (reuses slotA; hidb dead)
    k_conv<<<(int)(S / 256), 256, 0, stream>>>(xin, conv_w, conv_b, xc);

    // 4. x_proj: xdbl = xc @ xp_w^T
    gemm_nt<0><<<dim3(2, M / 64), 256, 0, stream>>>(
        xc, DD, xp_w, DD, RR + 2 * NNs, DD, nullptr, xdbl, 80);

    // 5. dt_proj + softplus -> dtf (b,t,d) (reuses slotB; xin dead)
    gemm_nt<2><<<dim3(DD / 64, M / 64), 256, 0, stream>>>(
        xdbl, 80, dt_w, RR, DD, RR, dt_b, dtf, DD);

    // 6. async-staged register-state scan + gating (zf -> gated y in place)
    k_scan<<<dim3(DD / 16, BB), 256, 0, stream>>>(dtf, xc, xdbl, A_log, Dp, zf);

    // 7. out_proj (MFMA, fp32 A cvt-staged) + bias + residual -> d_out
    gemm_mfma<3, true><<<dim3(DD / 128, M / 128), 256, 0, stream>>>(
        zf, outw_b, DD, out_b, res, out, nullptr);
}

// Round 8
// 413.871 us; speedup vs baseline: 1.0873x; 1.0873x over previous
//
#include <hip/hip_runtime.h>
#include <math.h>

#define BB 8
#define LL 1024
#define DD 768
#define NNs 16
#define RR 48

typedef __attribute__((ext_vector_type(8))) short bf16x8;
typedef __attribute__((ext_vector_type(4))) float f32x4;

__device__ __forceinline__ float silu_f(float v) { return v / (1.0f + __expf(-v)); }

__device__ __forceinline__ short f2bf(float f) {
    union { float f; unsigned u; } v; v.f = f;
    unsigned r = (v.u + 0x7fffu + ((v.u >> 16) & 1u)) >> 16;
    return (short)r;
}

__device__ __forceinline__ void async16(const void* g, void* l) {
    __builtin_amdgcn_global_load_lds((const __attribute__((address_space(1))) void*)g,
                                     (__attribute__((address_space(3))) void*)l,
                                     16, 0, 0);
}

// ---------------------------------------------------------------------------
// K0: fp32 -> bf16 weight conversion
// ---------------------------------------------------------------------------
__global__ __launch_bounds__(256) void k_cvt(const float* __restrict__ src,
                                             short* __restrict__ dst, int n4) {
    int i = blockIdx.x * 256 + threadIdx.x;
    if (i < n4) {
        float4 v = ((const float4*)src)[i];
        short4 o = { f2bf(v.x), f2bf(v.y), f2bf(v.z), f2bf(v.w) };
        ((short4*)dst)[i] = o;
    }
}

// ---------------------------------------------------------------------------
// K1: pos embedding (analytic; batch_params/has_velocity provably cancel) +
// residual + RMSNorm. res fp32, hidden bf16.
// ---------------------------------------------------------------------------
__global__ __launch_bounds__(256) void k_pos_rms(const float* __restrict__ x,
                                                 const float* __restrict__ norm_w,
                                                 float* __restrict__ res,
                                                 short* __restrict__ hidb) {
    int row = blockIdx.x;
    int l = row & (LL - 1);
    int d3 = l & 3;
    int w = (l >> 2) & 15;
    int h = l >> 6;
    float coord[3] = { h * (1.0f / 15.0f), w * (1.0f / 15.0f), d3 * (1.0f / 3.0f) };
    const float LOG1E4 = 9.210340371976184f;
    int t = threadIdx.x;
    float r[3];
    float s = 0.0f;
#pragma unroll
    for (int i = 0; i < 3; i++) {
        int j = t + i * 256;
        int c = j >> 8;
        int fp = j & 255;
        int f = fp & 127;
        float omega = __expf(-(f * (1.0f / 128.0f)) * LOG1E4);
        float arg = coord[c] * omega;
        float pv = (fp < 128) ? __sinf(arg) : __cosf(arg);
        float rv = x[(size_t)row * DD + j] + pv;
        r[i] = rv;
        s += rv * rv;
    }
#pragma unroll
    for (int off = 32; off; off >>= 1) s += __shfl_xor(s, off, 64);
    __shared__ float ls[4];
    if ((t & 63) == 0) ls[t >> 6] = s;
    __syncthreads();
    s = ls[0] + ls[1] + ls[2] + ls[3];
    float rs = rsqrtf(s * (1.0f / DD) + 1e-5f);
#pragma unroll
    for (int i = 0; i < 3; i++) {
        int j = t + i * 256;
        res[(size_t)row * DD + j] = r[i];
        hidb[(size_t)row * DD + j] = f2bf(r[i] * rs * norm_w[j]);
    }
}

// ---------------------------------------------------------------------------
// MFMA bf16 GEMM (NT), 128x128 tile, BK=32, 4 waves. AF32: A is fp32 and is
// converted to bf16 during LDS staging (out_proj path); else async16 staging.
// EPI 1 (in_proj): +bias; n<768 -> C0 (b,t,d); n>=768 -> C1 (b,t,d).
// EPI 3 (out_proj): +bias +resid -> C0.
// ---------------------------------------------------------------------------
template <int EPI, bool AF32>
__global__ __launch_bounds__(256) void gemm_mfma(const void* __restrict__ Ap,
                                                 const short* __restrict__ Bw,
                                                 int Kd,
                                                 const float* __restrict__ bias,
                                                 const float* __restrict__ resid,
                                                 float* __restrict__ C0,
                                                 float* __restrict__ C1) {
    __shared__ short As[4096];   // 128 rows x 32 k, fragment-ordered
    __shared__ short Bs[4096];
    int m0 = blockIdx.y * 128;
    int n0 = blockIdx.x * 128;
    int tid = threadIdx.x;
    int lane = tid & 63, wave = tid >> 6;
    int q = lane >> 4, r = lane & 15;
    int wm = wave >> 1, wn = wave & 1;

    const size_t Kb = (size_t)Kd * 2;
    const char* gB0 = (const char*)Bw + (size_t)(n0 + wave * 16 + r) * Kb + q * 16;
    const char* gB1 = gB0 + 64 * Kb;
    char* lB0 = (char*)Bs + wave * 1024;
    char* lB1 = lB0 + 4096;
    const char* gA0 = nullptr; const char* gA1 = nullptr;
    char* lA0 = nullptr; char* lA1 = nullptr;
    if (!AF32) {
        gA0 = (const char*)Ap + (size_t)(m0 + wave * 16 + r) * Kb + q * 16;
        gA1 = gA0 + 64 * Kb;
        lA0 = (char*)As + wave * 1024;
        lA1 = lA0 + 4096;
    }

    f32x4 acc[4][4] = {};

    for (int k0 = 0; k0 < Kd; k0 += 32) {
        if (AF32) {
            const float* Af = (const float*)Ap;
#pragma unroll
            for (int p = 0; p < 2; p++) {
                int m = m0 + (p * 4 + wave) * 16 + r;
                const float* src = Af + (size_t)m * Kd + k0 + q * 8;
                float4 v0 = *(const float4*)src;
                float4 v1 = *(const float4*)(src + 4);
                bf16x8 pk;
                pk[0] = f2bf(v0.x); pk[1] = f2bf(v0.y);
                pk[2] = f2bf(v0.z); pk[3] = f2bf(v0.w);
                pk[4] = f2bf(v1.x); pk[5] = f2bf(v1.y);
                pk[6] = f2bf(v1.z); pk[7] = f2bf(v1.w);
                *(bf16x8*)&As[p * 2048 + wave * 512 + lane * 8] = pk;
            }
        } else {
            async16(gA0, lA0); async16(gA1, lA1);
            gA0 += 64; gA1 += 64;
        }
        async16(gB0, lB0); async16(gB1, lB1);
        gB0 += 64; gB1 += 64;
        __syncthreads();
        bf16x8 af[4], bf[4];
#pragma unroll
        for (int a = 0; a < 4; a++)
            af[a] = *(const bf16x8*)&As[((wm * 4 + a) * 64 + q * 16 + r) * 8];
#pragma unroll
        for (int b = 0; b < 4; b++)
            bf[b] = *(const bf16x8*)&Bs[((wn * 4 + b) * 64 + q * 16 + r) * 8];
#pragma unroll
        for (int a = 0; a < 4; a++)
#pragma unroll
            for (int b = 0; b < 4; b++)
                acc[a][b] = __builtin_amdgcn_mfma_f32_16x16x32_bf16(
                    af[a], bf[b], acc[a][b], 0, 0, 0);
        __syncthreads();
    }

    // C/D layout: col(n) = lane&15, row(m) = (lane>>4)*4 + reg  [m89/m91]
#pragma unroll
    for (int a = 0; a < 4; a++) {
        int mrow = m0 + (wm * 4 + a) * 16 + q * 4;
#pragma unroll
        for (int b = 0; b < 4; b++) {
            int ncol = n0 + (wn * 4 + b) * 16 + r;
            float bb = bias[ncol];
            if (EPI == 1) {
                float* dst = (ncol < DD) ? (C0 + (size_t)mrow * DD + ncol)
                                         : (C1 + (size_t)mrow * DD + (ncol - DD));
#pragma unroll
                for (int e = 0; e < 4; e++)
                    dst[(size_t)e * DD] = acc[a][b][e] + bb;
            } else {
#pragma unroll
                for (int e = 0; e < 4; e++) {
                    size_t idx = (size_t)(mrow + e) * DD + ncol;
                    C0[idx] = acc[a][b][e] + bb + resid[idx];
                }
            }
        }
    }
}

// ---------------------------------------------------------------------------
// fp32 NT GEMM. MODE 0 (x_proj): plain store with n<N guard.
// MODE 2 (dt_proj): softplus, float4 store to (b,t,d).
// ---------------------------------------------------------------------------
template <int MODE>
__global__ __launch_bounds__(256) void gemm_nt(const float* __restrict__ A, int lda,
                                               const float* __restrict__ Bw, int ldb,
                                               int N, int Kd,
                                               const float* __restrict__ bias,
                                               float* __restrict__ C0, int ldc) {
    __shared__ __align__(16) float As[16][68];
    __shared__ __align__(16) float Bs[16][68];
    int m0 = blockIdx.y * 64;
    int n0 = blockIdx.x * 64;
    int t = threadIdx.x;
    int tx = t & 15, ty = t >> 4;
    int ar = t >> 2;
    int ak = (t & 3) * 4;
    float acc[4][4] = {};
    for (int k0 = 0; k0 < Kd; k0 += 16) {
        float4 av = *(const float4*)(A + (size_t)(m0 + ar) * lda + k0 + ak);
        int brow = n0 + ar;
        if (brow >= N) brow = N - 1;
        float4 bv = *(const float4*)(Bw + (size_t)brow * ldb + k0 + ak);
        As[ak + 0][ar] = av.x; As[ak + 1][ar] = av.y;
        As[ak + 2][ar] = av.z; As[ak + 3][ar] = av.w;
        Bs[ak + 0][ar] = bv.x; Bs[ak + 1][ar] = bv.y;
        Bs[ak + 2][ar] = bv.z; Bs[ak + 3][ar] = bv.w;
        __syncthreads();
#pragma unroll
        for (int kk = 0; kk < 16; kk++) {
            float4 a4 = *(const float4*)&As[kk][ty * 4];
            float4 b4 = *(const float4*)&Bs[kk][tx * 4];
            float aa[4] = { a4.x, a4.y, a4.z, a4.w };
            float bb[4] = { b4.x, b4.y, b4.z, b4.w };
#pragma unroll
            for (int i = 0; i < 4; i++)
#pragma unroll
                for (int j = 0; j < 4; j++) acc[i][j] += aa[i] * bb[j];
        }
        __syncthreads();
    }
    if (MODE == 0) {
#pragma unroll
        for (int i = 0; i < 4; i++) {
            int m = m0 + ty * 4 + i;
#pragma unroll
            for (int j = 0; j < 4; j++) {
                int n = n0 + tx * 4 + j;
                if (n < N) C0[(size_t)m * ldc + n] = acc[i][j];
            }
        }
    } else {
        float4 bi = *(const float4*)(bias + n0 + tx * 4);
        float bl[4] = { bi.x, bi.y, bi.z, bi.w };
#pragma unroll
        for (int i = 0; i < 4; i++) {
            int m = m0 + ty * 4 + i;
            float v[4];
#pragma unroll
            for (int j = 0; j < 4; j++) {
                float u = acc[i][j] + bl[j];
                v[j] = (u > 20.0f) ? u : log1pf(__expf(u));
            }
            float4 o = { v[0], v[1], v[2], v[3] };
            *(float4*)(C0 + (size_t)m * DD + n0 + tx * 4) = o;
        }
    }
}

// ---------------------------------------------------------------------------
// K3: depthwise causal conv (K=4) + bias + silu, (b,t,d) -> (b,t,d)
// ---------------------------------------------------------------------------
__global__ __launch_bounds__(256) void k_conv(const float* __restrict__ xin,
                                              const float* __restrict__ cw,
                                              const float* __restrict__ cb,
                                              float* __restrict__ xc) {
    size_t gid = (size_t)blockIdx.x * 256 + threadIdx.x;
    int d = (int)(gid % DD);
    int bt = (int)(gid / DD);
    int tt = bt & (LL - 1);
    float4 w = ((const float4*)cw)[d];
    const float* p = xin + (size_t)bt * DD + d;
    float acc = cb[d];
    if (tt >= 3) acc += p[-3 * DD] * w.x;
    if (tt >= 2) acc += p[-2 * DD] * w.y;
    if (tt >= 1) acc += p[-1 * DD] * w.z;
    acc += p[0] * w.w;
    xc[gid] = silu_f(acc);
}

// ---------------------------------------------------------------------------
// K5: register-state chunked selective scan, v5.
// Back to r6's direct-global-load structure (0 hot-loop LDS = 0 conflicts,
// compiler batches the independent loads), but 512-thread blocks:
// 16 d x 32 chunks of 32 t. Per-thread serial depth halves (64 iters vs 128)
// and co-resident waves double (2 blocks/CU at 64 KB LDS, VGPR<=128 via
// launch_bounds(512,4)) -> latency hiding via TLP, not manual staging.
// exp2f with log2(e) folded into Ac (native v_exp_f32).
// ---------------------------------------------------------------------------
__global__ __launch_bounds__(512, 4) void k_scan(const float* __restrict__ dtf,
                                                 const float* __restrict__ xc,
                                                 const float* __restrict__ xdbl,
                                                 const float* __restrict__ A_log,
                                                 const float* __restrict__ Dp,
                                                 float* __restrict__ zy) {
    __shared__ float Pl[32 * 16 * 16];     // [c][dl][n] 32 KB; becomes H
    __shared__ float Sl[32 * 16 * 16];     // 32 KB
    int b = blockIdx.y;
    int d0 = blockIdx.x * 16;
    int tid = threadIdx.x;
    int dl = tid & 15;
    int c = tid >> 4;                      // chunk 0..31 (32 t each)
    int d = d0 + dl;

    float Ac2[16];                         // -exp(A_log) * log2(e)
    {
        const float4* al = (const float4*)(A_log + d * NNs);
#pragma unroll
        for (int i = 0; i < 4; i++) {
            float4 v = al[i];
            Ac2[i * 4 + 0] = -__expf(v.x) * 1.44269504f;
            Ac2[i * 4 + 1] = -__expf(v.y) * 1.44269504f;
            Ac2[i * 4 + 2] = -__expf(v.z) * 1.44269504f;
            Ac2[i * 4 + 3] = -__expf(v.w) * 1.44269504f;
        }
    }
    size_t rb = ((size_t)(b * LL + c * 32)) * DD + d;
    const float* dtp = dtf + rb;
    const float* xcp = xc + rb;
    float* zp = zy + rb;
    const float* xrow = xdbl + ((size_t)(b * LL + c * 32)) * 80 + RR;

    // ---- Phase 1: local scan from zero state
    float P[16], S[16];
#pragma unroll
    for (int n = 0; n < 16; n++) { P[n] = 1.0f; S[n] = 0.0f; }
#pragma unroll 4
    for (int i = 0; i < 32; i++) {
        float dtv = dtp[(size_t)i * DD];
        float xcv = xcp[(size_t)i * DD];
        float dx = dtv * xcv;
        const float* Br = xrow + i * 80;
#pragma unroll
        for (int qq = 0; qq < 4; qq++) {
            float4 B4 = *(const float4*)(Br + qq * 4);
            float bl[4] = { B4.x, B4.y, B4.z, B4.w };
#pragma unroll
            for (int j = 0; j < 4; j++) {
                int n = qq * 4 + j;
                float e = exp2f(dtv * Ac2[n]);
                P[n] *= e;
                S[n] = e * S[n] + dx * bl[j];
            }
        }
    }
    {
        int base = (c * 16 + dl) * 16;
#pragma unroll
        for (int qq = 0; qq < 4; qq++) {
            float4 pv = { P[qq * 4], P[qq * 4 + 1], P[qq * 4 + 2], P[qq * 4 + 3] };
            float4 sv = { S[qq * 4], S[qq * 4 + 1], S[qq * 4 + 2], S[qq * 4 + 3] };
            *(float4*)&Pl[base + qq * 4] = pv;
            *(float4*)&Sl[base + qq * 4] = sv;
        }
    }
    __syncthreads();
    // ---- Phase 2: serial combine, thread per (d,n); H overwrites Pl
    if (tid < 256) {
        int d2 = tid >> 4, n2 = tid & 15;
        float hh = 0.0f;
#pragma unroll
        for (int cc = 0; cc < 32; cc++) {
            int idx = (cc * 16 + d2) * 16 + n2;
            float Pv = Pl[idx], Sv = Sl[idx];
            Pl[idx] = hh;
            hh = Pv * hh + Sv;
        }
    }
    __syncthreads();
    float h[16];
    {
        const float* hr = &Pl[(c * 16 + dl) * 16];
#pragma unroll
        for (int qq = 0; qq < 4; qq++) {
            float4 v = *(const float4*)(hr + qq * 4);
            h[qq * 4] = v.x; h[qq * 4 + 1] = v.y;
            h[qq * 4 + 2] = v.z; h[qq * 4 + 3] = v.w;
        }
    }
    float Dv = Dp[d];
    // ---- Phase 3: rescan from h_in, gate, write in place
#pragma unroll 2
    for (int i = 0; i < 32; i++) {
        float dtv = dtp[(size_t)i * DD];
        float xcv = xcp[(size_t)i * DD];
        float zv  = zp[(size_t)i * DD];
        float dx = dtv * xcv;
        float y = Dv * xcv;
        const float* Br = xrow + i * 80;
#pragma unroll
        for (int qq = 0; qq < 4; qq++) {
            float4 B4 = *(const float4*)(Br + qq * 4);
            float4 C4 = *(const float4*)(Br + 16 + qq * 4);
            float bl[4] = { B4.x, B4.y, B4.z, B4.w };
            float cl[4] = { C4.x, C4.y, C4.z, C4.w };
#pragma unroll
            for (int j = 0; j < 4; j++) {
                int n = qq * 4 + j;
                float e = exp2f(dtv * Ac2[n]);
                h[n] = e * h[n] + dx * bl[j];
                y += h[n] * cl[j];
            }
        }
        zp[(size_t)i * DD] = y * silu_f(zv);
    }
}

// ---------------------------------------------------------------------------
extern "C" void kernel_launch(void* const* d_in, const int* in_sizes, int n_in,
                              void* d_out, int out_size, void* d_ws, size_t ws_size,
                              hipStream_t stream) {
    const float* x      = (const float*)d_in[0];
    // d_in[1] batch_params, d_in[2] has_velocity: provably no effect
    const float* norm_w = (const float*)d_in[3];
    const float* in_w   = (const float*)d_in[4];
    const float* in_b   = (const float*)d_in[5];
    const float* conv_w = (const float*)d_in[6];
    const float* conv_b = (const float*)d_in[7];
    const float* xp_w   = (const float*)d_in[8];
    const float* dt_w   = (const float*)d_in[9];
    const float* dt_b   = (const float*)d_in[10];
    const float* A_log  = (const float*)d_in[11];
    const float* Dp     = (const float*)d_in[12];
    const float* out_w  = (const float*)d_in[13];
    const float* out_b  = (const float*)d_in[14];
    float* out = (float*)d_out;

    const size_t S = (size_t)BB * LL * DD;     // 6291456
    float* res   = (float*)d_ws;               // residual (fp32)
    float* slotA = res + S;                    // hidb (bf16) then xc (fp32)
    float* slotB = slotA + S;                  // xin then dtf (fp32)
    float* zf    = slotB + S;                  // z (b,t,d); gated y in place
    float* xdbl  = zf + S;                     // (B*L, 80)
    short* inw_b  = (short*)(xdbl + (size_t)BB * LL * 80);   // 1536x768 bf16
    short* outw_b = inw_b + 1536 * DD;                       // 768x768 bf16

    short* hidb = (short*)slotA;
    float* xc   = slotA;
    float* xin  = slotB;
    float* dtf  = slotB;

    const int M = BB * LL;                     // 8192

    // 0. weight conversions
    k_cvt<<<(1536 * DD / 4 + 255) / 256, 256, 0, stream>>>(in_w, inw_b, 1536 * DD / 4);
    k_cvt<<<(DD * DD / 4 + 255) / 256, 256, 0, stream>>>(out_w, outw_b, DD * DD / 4);

    // 1. pos + residual + rmsnorm (hidden bf16)
    k_pos_rms<<<M, 256, 0, stream>>>(x, norm_w, res, hidb);

    // 2. in_proj (MFMA): -> xin (b,t,d) | zf (b,t,d)
    gemm_mfma<1, false><<<dim3(1536 / 128, M / 128), 256, 0, stream>>>(
        hidb, inw_b, DD, in_b, nullptr, xin, zf);

    // 3. depthwise conv + silu: xin -> xc (reuses slotA; hidb dead)
    k_conv<<<(int)(S / 256), 256, 0, stream>>>(xin, conv_w, conv_b, xc);

    // 4. x_proj: xdbl = xc @ xp_w^T
    gemm_nt<0><<<dim3(2, M / 64), 256, 0, stream>>>(
        xc, DD, xp_w, DD, RR + 2 * NNs, DD, nullptr, xdbl, 80);

    // 5. dt_proj + softplus -> dtf (b,t,d) (reuses slotB; xin dead)
    gemm_nt<2><<<dim3(DD / 64, M / 64), 256, 0, stream>>>(
        xdbl, 80, dt_w, RR, DD, RR, dt_b, dtf, DD);

    // 6. register-state chunked scan v5 (512 thr) + gating (zf in place)
    k_scan<<<dim3(DD / 16, BB), 512, 0, stream>>>(dtf, xc, xdbl, A_log, Dp, zf);

    // 7. out_proj (MFMA, fp32 A cvt-staged) + bias + residual -> d_out
    gemm_mfma<3, true><<<dim3(DD / 128, M / 128), 256, 0, stream>>>(
        zf, outw_b, DD, out_b, res, out, nullptr);
}